// Round 1
// baseline (611.386 us; speedup 1.0000x reference)
//
#include <hip/hip_runtime.h>
#include <cstdint>

#define Hq 16
#define HKVn 8
#define DHn 128
#define Tn 2048
#define Bn 2
#define Dm 2048
#define BT (Bn*Tn)   // 4096

typedef __attribute__((ext_vector_type(8))) short bfrag8;   // 8 bf16 (4 VGPRs)
typedef __attribute__((ext_vector_type(4))) float facc4;    // 4 fp32 acc

__device__ __forceinline__ unsigned short f2bf(float f) {
    union { float f; unsigned int u; } v; v.f = f;
    unsigned int u = v.u;
    unsigned int r = (u + 0x7FFFu + ((u >> 16) & 1u)) >> 16;
    return (unsigned short)r;
}

// ---------------- fp32 -> bf16 convert (vectorized) ----------------
__global__ __launch_bounds__(256) void cvt_kernel(const float* __restrict__ in,
                                                  unsigned short* __restrict__ out, int n4) {
    int i = blockIdx.x * 256 + threadIdx.x;
    if (i < n4) {
        float4 x = ((const float4*)in)[i];
        ushort4 y;
        y.x = f2bf(x.x); y.y = f2bf(x.y); y.z = f2bf(x.z); y.w = f2bf(x.w);
        ((ushort4*)out)[i] = y;
    }
}

// ---------------- bf16 GEMM: C[M][N] = A[M][K] @ B[N][K]^T (fp32 out) ----------------
// m97 structure: 128x128 tile, BK=32, 4 waves (2x2), each wave 64x64 via 4x4 MFMA 16x16x32.
__global__ __launch_bounds__(256) void gemm_bt(const unsigned short* __restrict__ A,
                                               const unsigned short* __restrict__ Bm,
                                               float* __restrict__ C,
                                               int M, int N, int K) {
    __shared__ char smem[16384];   // As[128][32] bf16 @0, Bs[128][32] bf16 @8192
    int tid = threadIdx.x;
    int w = tid >> 6, lane = tid & 63, quad = lane >> 4, l15 = lane & 15;
    int wr = w >> 1, wc = w & 1;
    int rowBase = blockIdx.y * 128, colBase = blockIdx.x * 128;
    facc4 acc[4][4];
#pragma unroll
    for (int i = 0; i < 4; i++)
#pragma unroll
        for (int j = 0; j < 4; j++) acc[i][j] = facc4{0.f, 0.f, 0.f, 0.f};

    for (int k0 = 0; k0 < K; k0 += 32) {
        __syncthreads();
#pragma unroll
        for (int issue = 0; issue < 2; issue++) {
            int idx = issue * 256 + tid;            // 16B chunk id; row=idx/4, k8=idx%4
            const unsigned short* ga = A + (size_t)(rowBase + (idx >> 2)) * K + k0 + (idx & 3) * 8;
            __builtin_amdgcn_global_load_lds((const __attribute__((address_space(1))) void*)ga,
                (__attribute__((address_space(3))) void*)(smem + issue * 4096 + w * 1024), 16, 0, 0);
            const unsigned short* gb = Bm + (size_t)(colBase + (idx >> 2)) * K + k0 + (idx & 3) * 8;
            __builtin_amdgcn_global_load_lds((const __attribute__((address_space(1))) void*)gb,
                (__attribute__((address_space(3))) void*)(smem + 8192 + issue * 4096 + w * 1024), 16, 0, 0);
        }
        __syncthreads();
        bfrag8 af[4], bf[4];
#pragma unroll
        for (int i = 0; i < 4; i++)
            af[i] = *(const bfrag8*)(smem + ((wr * 64 + i * 16 + l15) * 32 + quad * 8) * 2);
#pragma unroll
        for (int j = 0; j < 4; j++)
            bf[j] = *(const bfrag8*)(smem + 8192 + ((wc * 64 + j * 16 + l15) * 32 + quad * 8) * 2);
#pragma unroll
        for (int i = 0; i < 4; i++)
#pragma unroll
            for (int j = 0; j < 4; j++)
                acc[i][j] = __builtin_amdgcn_mfma_f32_16x16x32_bf16(af[i], bf[j], acc[i][j], 0, 0, 0);
    }
    // epilogue: C/D layout row = quad*4 + r, col = lane&15 (verified m89/m91)
#pragma unroll
    for (int i = 0; i < 4; i++)
#pragma unroll
        for (int j = 0; j < 4; j++)
#pragma unroll
            for (int r = 0; r < 4; r++) {
                int row = rowBase + wr * 64 + i * 16 + quad * 4 + r;
                int col = colBase + wc * 64 + j * 16 + l15;
                C[(size_t)row * N + col] = acc[i][j][r];
            }
}

// ---------------- RMSNorm + RoPE, fp32 -> bf16, relayout per-head ----------------
// one wave per (token, head); lane handles dims d=lane and d=lane+64 (the RoPE pair)
__global__ __launch_bounds__(256) void normrope_kernel(const float* __restrict__ qkv,
                                                       const float* __restrict__ qw,
                                                       const float* __restrict__ kw,
                                                       unsigned short* __restrict__ q_bf,
                                                       unsigned short* __restrict__ k_bf) {
    int gw = (blockIdx.x * 256 + threadIdx.x) >> 6;
    int lane = threadIdx.x & 63;
    const float* src; unsigned short* dst; const float* wn; float scale; int t;
    if (gw < BT * Hq) {
        int bt = gw >> 4, h = gw & 15;
        int b = bt >> 11; t = bt & 2047;
        src = qkv + (size_t)bt * 4096 + h * 128;
        dst = q_bf + ((size_t)(b * Hq + h) * Tn + t) * 128;
        wn = qw; scale = 0.08838834764831845f;   // 1/sqrt(128) folded into q
    } else {
        int g2 = gw - BT * Hq;
        int bt = g2 >> 3, hk = g2 & 7;
        int b = bt >> 11; t = bt & 2047;
        src = qkv + (size_t)bt * 4096 + 2048 + hk * 128;
        dst = k_bf + ((size_t)(b * HKVn + hk) * Tn + t) * 128;
        wn = kw; scale = 1.0f;
    }
    float x0 = src[lane], x1 = src[lane + 64];
    float ss = x0 * x0 + x1 * x1;
#pragma unroll
    for (int off = 32; off > 0; off >>= 1) ss += __shfl_xor(ss, off);
    float inv = rsqrtf(ss * (1.0f / 128.0f) + 1e-6f);
    float n0 = x0 * inv * wn[lane];
    float n1 = x1 * inv * wn[lane + 64];
    // inv_freq[d] = theta^(-d/64) = 2^(-d*log2(theta)/64); log2(1e6)/64 = 0.311430758895690
    float fr = exp2f(-(float)lane * 0.3114307588956902f);
    float ang = (float)t * fr;
    float c = cosf(ang), s = sinf(ang);
    float y0 = (n0 * c - n1 * s) * scale;
    float y1 = (n1 * c + n0 * s) * scale;
    dst[lane] = f2bf(y0);
    dst[lane + 64] = f2bf(y1);
}

// ---------------- V slice: fp32 [bt][3072+hkv*128+d] -> bf16 vT[b][hkv][d][t] ----------------
__global__ __launch_bounds__(256) void vtrans_kernel(const float* __restrict__ qkv,
                                                     unsigned short* __restrict__ vT) {
    __shared__ unsigned short tile[64][130];   // +2 pad breaks transpose-read conflicts
    int tt = blockIdx.x & 31, hk = (blockIdx.x >> 5) & 7, b = blockIdx.x >> 8;
    int t0 = tt * 64;
#pragma unroll
    for (int i = 0; i < 32; i++) {
        int ix = threadIdx.x + i * 256;
        int tl = ix >> 7, d = ix & 127;
        tile[tl][d] = f2bf(qkv[(size_t)(b * Tn + t0 + tl) * 4096 + 3072 + hk * 128 + d]);
    }
    __syncthreads();
#pragma unroll
    for (int i = 0; i < 32; i++) {
        int ix = threadIdx.x + i * 256;
        int d = ix >> 6, tl = ix & 63;
        vT[((size_t)(b * HKVn + hk) * 128 + d) * Tn + t0 + tl] = tile[tl][d];
    }
}

// ---------------- flash attention: 64 q-rows/block, 32-key blocks, online softmax ----------------
__global__ __launch_bounds__(256) void attn_kernel(const unsigned short* __restrict__ q_bf,
                                                   const unsigned short* __restrict__ k_bf,
                                                   const unsigned short* __restrict__ vT_bf,
                                                   unsigned short* __restrict__ ctx) {
    __shared__ char smem[20480];  // Ks[32][128]@0 (8KB), Vt[128][32]@8192 (8KB), P[w][16][32]@16384 (4KB)
    int tid = threadIdx.x;
    int w = tid >> 6, lane = tid & 63, quad = lane >> 4, l15 = lane & 15;
    int idx = blockIdx.x;
    int qt = idx & 31, h = (idx >> 5) & 15, b = idx >> 9;
    int qtb = qt * 64;
    int hkv = h >> 1;  // G=2
    const unsigned short* qh = q_bf + ((size_t)(b * Hq + h) * Tn) * 128;
    const unsigned short* kh = k_bf + ((size_t)(b * HKVn + hkv) * Tn) * 128;
    const unsigned short* vh = vT_bf + ((size_t)(b * HKVn + hkv) * 128) * Tn;

    // Q fragments: A-layout, lane = row l15, elems d = f*32 + quad*8 + j (scale pre-folded)
    bfrag8 qf[4];
    int qrow = qtb + w * 16 + l15;
    const unsigned short* qp = qh + (size_t)qrow * 128;
#pragma unroll
    for (int f = 0; f < 4; f++) qf[f] = *(const bfrag8*)(qp + f * 32 + quad * 8);

    facc4 o[8];
#pragma unroll
    for (int j = 0; j < 8; j++) o[j] = facc4{0.f, 0.f, 0.f, 0.f};
    float mrow[4], lrow[4];
#pragma unroll
    for (int r = 0; r < 4; r++) { mrow[r] = -__builtin_inff(); lrow[r] = 0.0f; }
    int qmaxw = qtb + w * 16 + 15;
    int rowq0 = qtb + w * 16 + quad * 4;

    for (int kb = 0; kb < qtb + 64; kb += 32) {
        __syncthreads();
#pragma unroll
        for (int issue = 0; issue < 2; issue++) {
            int ix = issue * 256 + tid;
            // K tile [32 keys][128 d]
            const unsigned short* gk = kh + (size_t)(kb + (ix >> 4)) * 128 + (ix & 15) * 8;
            __builtin_amdgcn_global_load_lds((const __attribute__((address_space(1))) void*)gk,
                (__attribute__((address_space(3))) void*)(smem + issue * 4096 + w * 1024), 16, 0, 0);
            // Vt tile [128 d][32 keys]
            const unsigned short* gv = vh + (size_t)(ix >> 2) * Tn + kb + (ix & 3) * 8;
            __builtin_amdgcn_global_load_lds((const __attribute__((address_space(1))) void*)gv,
                (__attribute__((address_space(3))) void*)(smem + 8192 + issue * 4096 + w * 1024), 16, 0, 0);
        }
        __syncthreads();
        bool active = (kb <= qmaxw);
        float p0[4], p1[4];
        if (active) {
            facc4 sc[2];
#pragma unroll
            for (int c = 0; c < 2; c++) {
                facc4 s = facc4{0.f, 0.f, 0.f, 0.f};
#pragma unroll
                for (int f = 0; f < 4; f++) {
                    bfrag8 kf = *(const bfrag8*)(smem + ((c * 16 + l15) * 128 + f * 32 + quad * 8) * 2);
                    s = __builtin_amdgcn_mfma_f32_16x16x32_bf16(qf[f], kf, s, 0, 0, 0);
                }
                sc[c] = s;
            }
            // causal mask
#pragma unroll
            for (int c = 0; c < 2; c++)
#pragma unroll
                for (int r = 0; r < 4; r++) {
                    int kpos = kb + c * 16 + l15;
                    if (kpos > rowq0 + r) sc[c][r] = -__builtin_inff();
                }
            // row max across the quad's 16 lanes
            float mx[4];
#pragma unroll
            for (int r = 0; r < 4; r++) mx[r] = fmaxf(sc[0][r], sc[1][r]);
#pragma unroll
            for (int off = 8; off > 0; off >>= 1)
#pragma unroll
                for (int r = 0; r < 4; r++) mx[r] = fmaxf(mx[r], __shfl_xor(mx[r], off));
            float alpha[4];
#pragma unroll
            for (int r = 0; r < 4; r++) {
                float mn = fmaxf(mrow[r], mx[r]);
                alpha[r] = __expf(mrow[r] - mn);   // first block: exp(-inf)=0
                mrow[r] = mn;
            }
            float rs[4];
#pragma unroll
            for (int r = 0; r < 4; r++) {
                p0[r] = __expf(sc[0][r] - mrow[r]);
                p1[r] = __expf(sc[1][r] - mrow[r]);
                rs[r] = p0[r] + p1[r];
            }
#pragma unroll
            for (int off = 8; off > 0; off >>= 1)
#pragma unroll
                for (int r = 0; r < 4; r++) rs[r] += __shfl_xor(rs[r], off);
#pragma unroll
            for (int r = 0; r < 4; r++) lrow[r] = lrow[r] * alpha[r] + rs[r];
#pragma unroll
            for (int j = 0; j < 8; j++)
#pragma unroll
                for (int r = 0; r < 4; r++) o[j][r] = o[j][r] * alpha[r];
            // P (C-layout) -> LDS [16 q][32 k] bf16 (per-wave region)
#pragma unroll
            for (int r = 0; r < 4; r++) {
                *(unsigned short*)(smem + 16384 + w * 1024 + ((quad * 4 + r) * 32 + l15) * 2) = f2bf(p0[r]);
                *(unsigned short*)(smem + 16384 + w * 1024 + ((quad * 4 + r) * 32 + 16 + l15) * 2) = f2bf(p1[r]);
            }
        }
        __syncthreads();   // P visibility (uniform barrier)
        if (active) {
            // P as A-operand: lane reads P[l15][quad*8..+7]
            bfrag8 pf = *(const bfrag8*)(smem + 16384 + w * 1024 + (l15 * 32 + quad * 8) * 2);
#pragma unroll
            for (int j = 0; j < 8; j++) {
                bfrag8 vf = *(const bfrag8*)(smem + 8192 + ((j * 16 + l15) * 32 + quad * 8) * 2);
                o[j] = __builtin_amdgcn_mfma_f32_16x16x32_bf16(pf, vf, o[j], 0, 0, 0);
            }
        }
    }
    float invl[4];
#pragma unroll
    for (int r = 0; r < 4; r++) invl[r] = 1.0f / lrow[r];
#pragma unroll
    for (int j = 0; j < 8; j++)
#pragma unroll
        for (int r = 0; r < 4; r++) {
            int row = rowq0 + r;
            float val = o[j][r] * invl[r];
            ctx[((size_t)(b * Tn + row)) * 2048 + h * 128 + j * 16 + l15] = f2bf(val);
        }
}

extern "C" void kernel_launch(void* const* d_in, const int* in_sizes, int n_in,
                              void* d_out, int out_size, void* d_ws, size_t ws_size,
                              hipStream_t stream) {
    (void)in_sizes; (void)n_in; (void)out_size; (void)ws_size;
    const float* x  = (const float*)d_in[0];
    const float* wq = (const float*)d_in[1];
    const float* wk = (const float*)d_in[2];
    const float* wv = (const float*)d_in[3];
    const float* wo = (const float*)d_in[4];
    const float* qw = (const float*)d_in[5];
    const float* kw = (const float*)d_in[6];
    float* out = (float*)d_out;
    char* ws = (char*)d_ws;

    // workspace layout (bytes)
    unsigned short* x_bf    = (unsigned short*)(ws);               // 16.78 MB
    unsigned short* wqkv_bf = (unsigned short*)(ws + 16777216);    // 16.78 MB ([wq;wk;wv] rows)
    unsigned short* wo_bf   = (unsigned short*)(ws + 33554432);    //  8.39 MB
    float*          qkv_f   = (float*)(ws + 41943040);             // 67.11 MB [4096][4096]
    unsigned short* q_bf    = (unsigned short*)(ws + 109051904);   // 16.78 MB [B][H][T][128]
    unsigned short* k_bf    = (unsigned short*)(ws + 125829120);   //  8.39 MB [B][HKV][T][128]
    unsigned short* vT_bf   = (unsigned short*)(ws + 134217728);   //  8.39 MB [B][HKV][128][T]
    unsigned short* ctx_bf  = (unsigned short*)(ws + 142606336);   // 16.78 MB [4096][2048]

    // 1. converts
    cvt_kernel<<<8192, 256, 0, stream>>>(x, x_bf, 2097152);
    cvt_kernel<<<4096, 256, 0, stream>>>(wq, wqkv_bf, 1048576);
    cvt_kernel<<<2048, 256, 0, stream>>>(wk, wqkv_bf + 4194304, 524288);
    cvt_kernel<<<2048, 256, 0, stream>>>(wv, wqkv_bf + 6291456, 524288);
    cvt_kernel<<<4096, 256, 0, stream>>>(wo, wo_bf, 1048576);
    // 2. fused QKV projection: [4096 tok][4096 = 2048q|1024k|1024v]
    gemm_bt<<<dim3(32, 32), 256, 0, stream>>>(x_bf, wqkv_bf, qkv_f, 4096, 4096, 2048);
    // 3. RMSNorm + RoPE (+1/sqrt(128) into q), relayout to bf16
    normrope_kernel<<<24576, 256, 0, stream>>>(qkv_f, qw, kw, q_bf, k_bf);
    vtrans_kernel<<<512, 256, 0, stream>>>(qkv_f, vT_bf);
    // 4. causal GQA flash attention -> ctx bf16 [tok][H*DH]
    attn_kernel<<<1024, 256, 0, stream>>>(q_bf, k_bf, vT_bf, ctx_bf);
    // 5. output projection -> fp32 d_out
    gemm_bt<<<dim3(16, 32), 256, 0, stream>>>(ctx_bf, wo_bf, out, 4096, 2048, 2048);
}

// Round 2
// 415.490 us; speedup vs baseline: 1.4715x; 1.4715x over previous
//
#include <hip/hip_runtime.h>
#include <cstdint>

#define Hq 16
#define HKVn 8
#define DHn 128
#define Tn 2048
#define Bn 2
#define Dm 2048
#define BT (Bn*Tn)   // 4096

typedef __attribute__((ext_vector_type(8))) short bfrag8;   // 8 bf16 (4 VGPRs)
typedef __attribute__((ext_vector_type(4))) float facc4;    // 4 fp32 acc
typedef __attribute__((ext_vector_type(4))) _Float16 f16x4; // 4 fp16 (2 VGPRs)
typedef __attribute__((ext_vector_type(8))) _Float16 f16x8; // 8 fp16 (4 VGPRs)

__device__ __forceinline__ unsigned short f2bf(float f) {
    union { float f; unsigned int u; } v; v.f = f;
    unsigned int u = v.u;
    unsigned int r = (u + 0x7FFFu + ((u >> 16) & 1u)) >> 16;
    return (unsigned short)r;
}

// ---------------- fp32 -> bf16 convert (vectorized) ----------------
__global__ __launch_bounds__(256) void cvt_kernel(const float* __restrict__ in,
                                                  unsigned short* __restrict__ out, int n4) {
    int i = blockIdx.x * 256 + threadIdx.x;
    if (i < n4) {
        float4 x = ((const float4*)in)[i];
        ushort4 y;
        y.x = f2bf(x.x); y.y = f2bf(x.y); y.z = f2bf(x.z); y.w = f2bf(x.w);
        ((ushort4*)out)[i] = y;
    }
}

// ---------------- bf16 GEMM: C[M][N] = A[M][K] @ B[N][K]^T (fp32 out) ----------------
__global__ __launch_bounds__(256) void gemm_bt(const unsigned short* __restrict__ A,
                                               const unsigned short* __restrict__ Bm,
                                               float* __restrict__ C,
                                               int M, int N, int K) {
    __shared__ char smem[16384];   // As[128][32] bf16 @0, Bs[128][32] bf16 @8192
    int tid = threadIdx.x;
    int w = tid >> 6, lane = tid & 63, quad = lane >> 4, l15 = lane & 15;
    int wr = w >> 1, wc = w & 1;
    int rowBase = blockIdx.y * 128, colBase = blockIdx.x * 128;
    facc4 acc[4][4];
#pragma unroll
    for (int i = 0; i < 4; i++)
#pragma unroll
        for (int j = 0; j < 4; j++) acc[i][j] = facc4{0.f, 0.f, 0.f, 0.f};

    for (int k0 = 0; k0 < K; k0 += 32) {
        __syncthreads();
#pragma unroll
        for (int issue = 0; issue < 2; issue++) {
            int idx = issue * 256 + tid;
            const unsigned short* ga = A + (size_t)(rowBase + (idx >> 2)) * K + k0 + (idx & 3) * 8;
            __builtin_amdgcn_global_load_lds((const __attribute__((address_space(1))) void*)ga,
                (__attribute__((address_space(3))) void*)(smem + issue * 4096 + w * 1024), 16, 0, 0);
            const unsigned short* gb = Bm + (size_t)(colBase + (idx >> 2)) * K + k0 + (idx & 3) * 8;
            __builtin_amdgcn_global_load_lds((const __attribute__((address_space(1))) void*)gb,
                (__attribute__((address_space(3))) void*)(smem + 8192 + issue * 4096 + w * 1024), 16, 0, 0);
        }
        __syncthreads();
        bfrag8 af[4], bf[4];
#pragma unroll
        for (int i = 0; i < 4; i++)
            af[i] = *(const bfrag8*)(smem + ((wr * 64 + i * 16 + l15) * 32 + quad * 8) * 2);
#pragma unroll
        for (int j = 0; j < 4; j++)
            bf[j] = *(const bfrag8*)(smem + 8192 + ((wc * 64 + j * 16 + l15) * 32 + quad * 8) * 2);
#pragma unroll
        for (int i = 0; i < 4; i++)
#pragma unroll
            for (int j = 0; j < 4; j++)
                acc[i][j] = __builtin_amdgcn_mfma_f32_16x16x32_bf16(af[i], bf[j], acc[i][j], 0, 0, 0);
    }
#pragma unroll
    for (int i = 0; i < 4; i++)
#pragma unroll
        for (int j = 0; j < 4; j++)
#pragma unroll
            for (int r = 0; r < 4; r++) {
                int row = rowBase + wr * 64 + i * 16 + quad * 4 + r;
                int col = colBase + wc * 64 + j * 16 + l15;
                C[(size_t)row * N + col] = acc[i][j][r];
            }
}

// K tiled-layout element offset within a (b,hkv) plane.
// Tile = 64 tokens x 128 dims, 8192 ushorts, staged linearly to LDS.
// chunk(kc,f,quad,l15) = ((kc*4+f)*64 + quad*16 + l15), elem = chunk*8 + j
// holds K[t=kc*16+l15][d=f*32+quad*8+j]
__device__ __forceinline__ size_t koff_tiled(int t, int d) {
    int kc = (t >> 4) & 3, l15 = t & 15;
    int f = d >> 5, qd = (d >> 3) & 3, j = d & 7;
    return (size_t)(t >> 6) * 8192 + ((((kc * 4 + f) * 64 + qd * 16 + l15) << 3) + j);
}

// ---------------- RMSNorm + RoPE, fp32 -> bf16, relayout per-head ----------------
__global__ __launch_bounds__(256) void normrope_kernel(const float* __restrict__ qkv,
                                                       const float* __restrict__ qw,
                                                       const float* __restrict__ kw,
                                                       unsigned short* __restrict__ q_bf,
                                                       unsigned short* __restrict__ k_bf) {
    int gw = (blockIdx.x * 256 + threadIdx.x) >> 6;
    int lane = threadIdx.x & 63;
    const float* src; const float* wn; float scale; int t;
    bool isq = (gw < BT * Hq);
    unsigned short* qdst = nullptr; unsigned short* kbase = nullptr;
    if (isq) {
        int bt = gw >> 4, h = gw & 15;
        int b = bt >> 11; t = bt & 2047;
        src = qkv + (size_t)bt * 4096 + h * 128;
        qdst = q_bf + ((size_t)(b * Hq + h) * Tn + t) * 128;
        wn = qw; scale = 0.08838834764831845f;   // 1/sqrt(128) folded into q
    } else {
        int g2 = gw - BT * Hq;
        int bt = g2 >> 3, hk = g2 & 7;
        int b = bt >> 11; t = bt & 2047;
        src = qkv + (size_t)bt * 4096 + 2048 + hk * 128;
        kbase = k_bf + (size_t)(b * HKVn + hk) * Tn * 128;
        wn = kw; scale = 1.0f;
    }
    float x0 = src[lane], x1 = src[lane + 64];
    float ss = x0 * x0 + x1 * x1;
#pragma unroll
    for (int off = 32; off > 0; off >>= 1) ss += __shfl_xor(ss, off);
    float inv = rsqrtf(ss * (1.0f / 128.0f) + 1e-6f);
    float n0 = x0 * inv * wn[lane];
    float n1 = x1 * inv * wn[lane + 64];
    float fr = exp2f(-(float)lane * 0.3114307588956902f);
    float ang = (float)t * fr;
    float c = cosf(ang), s = sinf(ang);
    float y0 = (n0 * c - n1 * s) * scale;
    float y1 = (n1 * c + n0 * s) * scale;
    if (isq) {
        qdst[lane] = f2bf(y0);
        qdst[lane + 64] = f2bf(y1);
    } else {
        kbase[koff_tiled(t, lane)] = f2bf(y0);
        kbase[koff_tiled(t, lane + 64)] = f2bf(y1);
    }
}

// ---------------- V slice: fp32 -> fp16 tiled layout for PV A-operand ----------------
// Tile = 64 keys x 128 dims, 8192 halfs. chunk(dblk,kcp,quad,l15) holds
// V[k = kcp*32 + h*16 + quad*4 + j][d = dblk*16 + l15] at elem h*4+j.
__global__ __launch_bounds__(256) void vtrans_kernel(const float* __restrict__ qkv,
                                                     _Float16* __restrict__ vT) {
    __shared__ _Float16 tile[64 * 128];
    int tid = threadIdx.x;
    int t64 = blockIdx.x & 31, hk = (blockIdx.x >> 5) & 7, b = blockIdx.x >> 8;
    int t0 = t64 * 64;
#pragma unroll
    for (int i = 0; i < 8; i++) {
        int ix = i * 256 + tid;           // 2048 float4 chunks
        int tl = ix >> 5, dc = (ix & 31) * 4;
        float4 v = *(const float4*)(qkv + (size_t)(b * Tn + t0 + tl) * 4096 + 3072 + hk * 128 + dc);
        tile[tl * 128 + dc + 0] = (_Float16)v.x;
        tile[tl * 128 + dc + 1] = (_Float16)v.y;
        tile[tl * 128 + dc + 2] = (_Float16)v.z;
        tile[tl * 128 + dc + 3] = (_Float16)v.w;
    }
    __syncthreads();
    _Float16* out = vT + (((size_t)(b * HKVn + hk) * 32 + t64) * 8192);
#pragma unroll
    for (int i = 0; i < 4; i++) {
        int oc = i * 256 + tid;           // 1024 16B chunks
        int dblk = oc >> 7, kcp = (oc >> 6) & 1, qd = (oc >> 4) & 3, l15 = oc & 15;
        f16x8 st;
#pragma unroll
        for (int e = 0; e < 8; e++) {
            int h = e >> 2, j = e & 3;
            int t = kcp * 32 + h * 16 + qd * 4 + j;
            int d = dblk * 16 + l15;
            st[e] = tile[t * 128 + d];
        }
        *(f16x8*)(out + oc * 8) = st;
    }
}

// ---------------- flash attention v2: S^T trick, 128 q-rows/block, 64-key iters --------
__global__ __launch_bounds__(256) void attn_kernel(const unsigned short* __restrict__ q_bf,
                                                   const unsigned short* __restrict__ k_glob,
                                                   const _Float16* __restrict__ v_glob,
                                                   unsigned short* __restrict__ ctx) {
    __shared__ char smem[32768];   // K tile 16KB @0, V tile 16KB @16384
    int tid = threadIdx.x;
    int w = tid >> 6, lane = tid & 63, quad = lane >> 4, l15 = lane & 15;
    int bid = blockIdx.x;
    int qblk = 15 - (bid & 15);          // long blocks dispatch first
    int h = (bid >> 4) & 15, b = bid >> 8;
    int hkv = h >> 1;
    int qb = qblk * 128;
    int qw0 = qb + w * 32;               // this wave's first q row

    const unsigned short* qp = q_bf + (size_t)(b * Hq + h) * Tn * 128;
    const unsigned short* ktile = k_glob + (size_t)(b * HKVn + hkv) * 32 * 8192;
    const _Float16* vtile = v_glob + (size_t)(b * HKVn + hkv) * 32 * 8192;

    // Q fragments (B-operand of S^T mfma): lane l15 = q row, d = f*32+quad*8+j
    bfrag8 qf[2][4];
#pragma unroll
    for (int g = 0; g < 2; g++) {
        int row = qw0 + g * 16 + l15;
#pragma unroll
        for (int f = 0; f < 4; f++)
            qf[g][f] = *(const bfrag8*)(qp + (size_t)row * 128 + f * 32 + quad * 8);
    }

    facc4 o0[8], o1[8];
#pragma unroll
    for (int j = 0; j < 8; j++) { o0[j] = facc4{0.f,0.f,0.f,0.f}; o1[j] = facc4{0.f,0.f,0.f,0.f}; }
    float m0 = -__builtin_inff(), m1 = -__builtin_inff(), l0 = 0.f, l1 = 0.f;

    int nkb = qb / 64 + 2;
    for (int ib = 0; ib < nkb; ib++) {
        int kb = ib * 64;
        __syncthreads();
#pragma unroll
        for (int i = 0; i < 4; i++) {
            const unsigned short* gk = ktile + (size_t)ib * 8192 + (i * 256 + tid) * 8;
            __builtin_amdgcn_global_load_lds((const __attribute__((address_space(1))) void*)gk,
                (__attribute__((address_space(3))) void*)(smem + i * 4096 + w * 1024), 16, 0, 0);
            const _Float16* gv = vtile + (size_t)ib * 8192 + (i * 256 + tid) * 8;
            __builtin_amdgcn_global_load_lds((const __attribute__((address_space(1))) void*)gv,
                (__attribute__((address_space(3))) void*)(smem + 16384 + i * 4096 + w * 1024), 16, 0, 0);
        }
        __syncthreads();
        if (kb <= qw0 + 31) {
            // S^T = K·Q^T : lane holds S^T[k = kb+kc*16+quad*4+r][q = qbase+l15]
            facc4 s0[4], s1[4];
#pragma unroll
            for (int kc = 0; kc < 4; kc++) {
                bfrag8 kf[4];
#pragma unroll
                for (int f = 0; f < 4; f++)
                    kf[f] = *(const bfrag8*)(smem + (((kc * 4 + f) * 64 + lane) << 4));
                facc4 a = facc4{0.f,0.f,0.f,0.f}, bq = facc4{0.f,0.f,0.f,0.f};
#pragma unroll
                for (int f = 0; f < 4; f++) {
                    a  = __builtin_amdgcn_mfma_f32_16x16x32_bf16(kf[f], qf[0][f], a, 0, 0, 0);
                    bq = __builtin_amdgcn_mfma_f32_16x16x32_bf16(kf[f], qf[1][f], bq, 0, 0, 0);
                }
                s0[kc] = a; s1[kc] = bq;
            }
            if (kb + 63 > qw0) {   // diagonal: apply causal mask
                int q0 = qw0 + l15, q1 = q0 + 16;
#pragma unroll
                for (int kc = 0; kc < 4; kc++)
#pragma unroll
                    for (int r = 0; r < 4; r++) {
                        int k = kb + kc * 16 + quad * 4 + r;
                        if (k > q0) s0[kc][r] = -__builtin_inff();
                        if (k > q1) s1[kc][r] = -__builtin_inff();
                    }
            }
            // row max (per lane column q): 16 regs + 2 cross-quad shuffles
            float mx0 = s0[0][0], mx1 = s1[0][0];
#pragma unroll
            for (int kc = 0; kc < 4; kc++)
#pragma unroll
                for (int r = 0; r < 4; r++) {
                    mx0 = fmaxf(mx0, s0[kc][r]); mx1 = fmaxf(mx1, s1[kc][r]);
                }
            mx0 = fmaxf(mx0, __shfl_xor(mx0, 16)); mx0 = fmaxf(mx0, __shfl_xor(mx0, 32));
            mx1 = fmaxf(mx1, __shfl_xor(mx1, 16)); mx1 = fmaxf(mx1, __shfl_xor(mx1, 32));
            float mn0 = fmaxf(m0, mx0), mn1 = fmaxf(m1, mx1);
            float alpha0 = __expf(m0 - mn0), alpha1 = __expf(m1 - mn1);
            m0 = mn0; m1 = mn1;
            float rs0 = 0.f, rs1 = 0.f;
#pragma unroll
            for (int kc = 0; kc < 4; kc++)
#pragma unroll
                for (int r = 0; r < 4; r++) {
                    s0[kc][r] = __expf(s0[kc][r] - m0); rs0 += s0[kc][r];
                    s1[kc][r] = __expf(s1[kc][r] - m1); rs1 += s1[kc][r];
                }
            rs0 += __shfl_xor(rs0, 16); rs0 += __shfl_xor(rs0, 32);
            rs1 += __shfl_xor(rs1, 16); rs1 += __shfl_xor(rs1, 32);
            l0 = l0 * alpha0 + rs0; l1 = l1 * alpha1 + rs1;
#pragma unroll
            for (int j = 0; j < 8; j++)
#pragma unroll
                for (int r = 0; r < 4; r++) { o0[j][r] *= alpha0; o1[j][r] *= alpha1; }
            // P^T C-regs -> fp16 B-operands (k = quad*4+j matches 16x16x16 layout)
            f16x4 pb0[4], pb1[4];
#pragma unroll
            for (int kc = 0; kc < 4; kc++) {
                pb0[kc] = f16x4{(_Float16)s0[kc][0], (_Float16)s0[kc][1],
                                (_Float16)s0[kc][2], (_Float16)s0[kc][3]};
                pb1[kc] = f16x4{(_Float16)s1[kc][0], (_Float16)s1[kc][1],
                                (_Float16)s1[kc][2], (_Float16)s1[kc][3]};
            }
            // PV: O^T[d][q] += V^T[d][k]·P^T[k][q]
#pragma unroll
            for (int kcp = 0; kcp < 2; kcp++)
#pragma unroll
                for (int dblk = 0; dblk < 8; dblk++) {
                    f16x8 vv = *(const f16x8*)(smem + 16384 + (((dblk * 2 + kcp) * 64 + lane) << 4));
                    f16x4 a0 = f16x4{vv[0], vv[1], vv[2], vv[3]};
                    f16x4 a1 = f16x4{vv[4], vv[5], vv[6], vv[7]};
                    o0[dblk] = __builtin_amdgcn_mfma_f32_16x16x16f16(a0, pb0[kcp*2],   o0[dblk], 0, 0, 0);
                    o0[dblk] = __builtin_amdgcn_mfma_f32_16x16x16f16(a1, pb0[kcp*2+1], o0[dblk], 0, 0, 0);
                    o1[dblk] = __builtin_amdgcn_mfma_f32_16x16x16f16(a0, pb1[kcp*2],   o1[dblk], 0, 0, 0);
                    o1[dblk] = __builtin_amdgcn_mfma_f32_16x16x16f16(a1, pb1[kcp*2+1], o1[dblk], 0, 0, 0);
                }
        }
    }
    // epilogue: O^T C-layout: lane holds O[q = base+l15][d = dblk*16+quad*4+r]
    float inv0 = 1.0f / l0, inv1 = 1.0f / l1;
#pragma unroll
    for (int g = 0; g < 2; g++) {
        int q = qw0 + g * 16 + l15;
        float invl = g ? inv1 : inv0;
#pragma unroll
        for (int dblk = 0; dblk < 8; dblk++) {
            facc4 ov = g ? o1[dblk] : o0[dblk];
            ushort4 st;
            st.x = f2bf(ov[0] * invl); st.y = f2bf(ov[1] * invl);
            st.z = f2bf(ov[2] * invl); st.w = f2bf(ov[3] * invl);
            *(ushort4*)(ctx + ((size_t)(b * Tn + q)) * 2048 + h * 128 + dblk * 16 + quad * 4) = st;
        }
    }
}

extern "C" void kernel_launch(void* const* d_in, const int* in_sizes, int n_in,
                              void* d_out, int out_size, void* d_ws, size_t ws_size,
                              hipStream_t stream) {
    (void)in_sizes; (void)n_in; (void)out_size; (void)ws_size;
    const float* x  = (const float*)d_in[0];
    const float* wq = (const float*)d_in[1];
    const float* wk = (const float*)d_in[2];
    const float* wv = (const float*)d_in[3];
    const float* wo = (const float*)d_in[4];
    const float* qw = (const float*)d_in[5];
    const float* kw = (const float*)d_in[6];
    float* out = (float*)d_out;
    char* ws = (char*)d_ws;

    unsigned short* x_bf    = (unsigned short*)(ws);               // 16.78 MB
    unsigned short* wqkv_bf = (unsigned short*)(ws + 16777216);    // 16.78 MB
    unsigned short* wo_bf   = (unsigned short*)(ws + 33554432);    //  8.39 MB
    float*          qkv_f   = (float*)(ws + 41943040);             // 67.11 MB
    unsigned short* q_bf    = (unsigned short*)(ws + 109051904);   // 16.78 MB [B][H][T][128]
    unsigned short* k_bf    = (unsigned short*)(ws + 125829120);   //  8.39 MB tiled
    _Float16*       vT_f16  = (_Float16*)(ws + 134217728);         //  8.39 MB tiled fp16
    unsigned short* ctx_bf  = (unsigned short*)(ws + 142606336);   // 16.78 MB [4096][2048]

    cvt_kernel<<<8192, 256, 0, stream>>>(x, x_bf, 2097152);
    cvt_kernel<<<4096, 256, 0, stream>>>(wq, wqkv_bf, 1048576);
    cvt_kernel<<<2048, 256, 0, stream>>>(wk, wqkv_bf + 4194304, 524288);
    cvt_kernel<<<2048, 256, 0, stream>>>(wv, wqkv_bf + 6291456, 524288);
    cvt_kernel<<<4096, 256, 0, stream>>>(wo, wo_bf, 1048576);
    gemm_bt<<<dim3(32, 32), 256, 0, stream>>>(x_bf, wqkv_bf, qkv_f, 4096, 4096, 2048);
    normrope_kernel<<<24576, 256, 0, stream>>>(qkv_f, qw, kw, q_bf, k_bf);
    vtrans_kernel<<<512, 256, 0, stream>>>(qkv_f, vT_f16);
    attn_kernel<<<512, 256, 0, stream>>>(q_bf, k_bf, vT_f16, ctx_bf);
    gemm_bt<<<dim3(16, 32), 256, 0, stream>>>(ctx_bf, wo_bf, out, 4096, 2048, 2048);
}

// Round 3
// 374.917 us; speedup vs baseline: 1.6307x; 1.1082x over previous
//
#include <hip/hip_runtime.h>
#include <cstdint>

#define Hq 16
#define HKVn 8
#define DHn 128
#define Tn 2048
#define Bn 2
#define Dm 2048
#define BT (Bn*Tn)   // 4096

typedef __attribute__((ext_vector_type(8))) short bfrag8;   // 8 bf16 (4 VGPRs)
typedef __attribute__((ext_vector_type(4))) float facc4;    // 4 fp32 acc
typedef __attribute__((ext_vector_type(4))) _Float16 f16x4; // 4 fp16 (2 VGPRs)
typedef __attribute__((ext_vector_type(8))) _Float16 f16x8; // 8 fp16 (4 VGPRs)

__device__ __forceinline__ unsigned short f2bf(float f) {
    union { float f; unsigned int u; } v; v.f = f;
    unsigned int u = v.u;
    unsigned int r = (u + 0x7FFFu + ((u >> 16) & 1u)) >> 16;
    return (unsigned short)r;
}

// ---------------- fp32 -> bf16 convert (vectorized) ----------------
__global__ __launch_bounds__(256) void cvt_kernel(const float* __restrict__ in,
                                                  unsigned short* __restrict__ out, int n4) {
    int i = blockIdx.x * 256 + threadIdx.x;
    if (i < n4) {
        float4 x = ((const float4*)in)[i];
        ushort4 y;
        y.x = f2bf(x.x); y.y = f2bf(x.y); y.z = f2bf(x.z); y.w = f2bf(x.w);
        ((ushort4*)out)[i] = y;
    }
}

// ---------------- bf16 GEMM: C[M][N] = A[M][K] @ B[N][K]^T (fp32 out) ----------------
__global__ __launch_bounds__(256) void gemm_bt(const unsigned short* __restrict__ A,
                                               const unsigned short* __restrict__ Bm,
                                               float* __restrict__ C,
                                               int M, int N, int K) {
    __shared__ char smem[16384];   // As[128][32] bf16 @0, Bs[128][32] bf16 @8192
    int tid = threadIdx.x;
    int w = tid >> 6, lane = tid & 63, quad = lane >> 4, l15 = lane & 15;
    int wr = w >> 1, wc = w & 1;
    int rowBase = blockIdx.y * 128, colBase = blockIdx.x * 128;
    facc4 acc[4][4];
#pragma unroll
    for (int i = 0; i < 4; i++)
#pragma unroll
        for (int j = 0; j < 4; j++) acc[i][j] = facc4{0.f, 0.f, 0.f, 0.f};

    for (int k0 = 0; k0 < K; k0 += 32) {
        __syncthreads();
#pragma unroll
        for (int issue = 0; issue < 2; issue++) {
            int idx = issue * 256 + tid;
            const unsigned short* ga = A + (size_t)(rowBase + (idx >> 2)) * K + k0 + (idx & 3) * 8;
            __builtin_amdgcn_global_load_lds((const __attribute__((address_space(1))) void*)ga,
                (__attribute__((address_space(3))) void*)(smem + issue * 4096 + w * 1024), 16, 0, 0);
            const unsigned short* gb = Bm + (size_t)(colBase + (idx >> 2)) * K + k0 + (idx & 3) * 8;
            __builtin_amdgcn_global_load_lds((const __attribute__((address_space(1))) void*)gb,
                (__attribute__((address_space(3))) void*)(smem + 8192 + issue * 4096 + w * 1024), 16, 0, 0);
        }
        __syncthreads();
        bfrag8 af[4], bf[4];
#pragma unroll
        for (int i = 0; i < 4; i++)
            af[i] = *(const bfrag8*)(smem + ((wr * 64 + i * 16 + l15) * 32 + quad * 8) * 2);
#pragma unroll
        for (int j = 0; j < 4; j++)
            bf[j] = *(const bfrag8*)(smem + 8192 + ((wc * 64 + j * 16 + l15) * 32 + quad * 8) * 2);
#pragma unroll
        for (int i = 0; i < 4; i++)
#pragma unroll
            for (int j = 0; j < 4; j++)
                acc[i][j] = __builtin_amdgcn_mfma_f32_16x16x32_bf16(af[i], bf[j], acc[i][j], 0, 0, 0);
    }
#pragma unroll
    for (int i = 0; i < 4; i++)
#pragma unroll
        for (int j = 0; j < 4; j++)
#pragma unroll
            for (int r = 0; r < 4; r++) {
                int row = rowBase + wr * 64 + i * 16 + quad * 4 + r;
                int col = colBase + wc * 64 + j * 16 + l15;
                C[(size_t)row * N + col] = acc[i][j][r];
            }
}

// K tiled-layout element offset within a (b,hkv) plane.
// Tile = 64 tokens x 128 dims, 8192 ushorts, staged linearly to LDS.
// chunk(kc,f,quad,l15) = ((kc*4+f)*64 + quad*16 + l15), elem = chunk*8 + j
// holds K[t=kc*16+l15][d=f*32+quad*8+j]
__device__ __forceinline__ size_t koff_tiled(int t, int d) {
    int kc = (t >> 4) & 3, l15 = t & 15;
    int f = d >> 5, qd = (d >> 3) & 3, j = d & 7;
    return (size_t)(t >> 6) * 8192 + ((((kc * 4 + f) * 64 + qd * 16 + l15) << 3) + j);
}

// ---------------- RMSNorm + RoPE, fp32 -> bf16, relayout per-head ----------------
__global__ __launch_bounds__(256) void normrope_kernel(const float* __restrict__ qkv,
                                                       const float* __restrict__ qw,
                                                       const float* __restrict__ kw,
                                                       unsigned short* __restrict__ q_bf,
                                                       unsigned short* __restrict__ k_bf) {
    int gw = (blockIdx.x * 256 + threadIdx.x) >> 6;
    int lane = threadIdx.x & 63;
    const float* src; const float* wn; float scale; int t;
    bool isq = (gw < BT * Hq);
    unsigned short* qdst = nullptr; unsigned short* kbase = nullptr;
    if (isq) {
        int bt = gw >> 4, h = gw & 15;
        int b = bt >> 11; t = bt & 2047;
        src = qkv + (size_t)bt * 4096 + h * 128;
        qdst = q_bf + ((size_t)(b * Hq + h) * Tn + t) * 128;
        wn = qw; scale = 0.08838834764831845f;   // 1/sqrt(128) folded into q
    } else {
        int g2 = gw - BT * Hq;
        int bt = g2 >> 3, hk = g2 & 7;
        int b = bt >> 11; t = bt & 2047;
        src = qkv + (size_t)bt * 4096 + 2048 + hk * 128;
        kbase = k_bf + (size_t)(b * HKVn + hk) * Tn * 128;
        wn = kw; scale = 1.0f;
    }
    float x0 = src[lane], x1 = src[lane + 64];
    float ss = x0 * x0 + x1 * x1;
#pragma unroll
    for (int off = 32; off > 0; off >>= 1) ss += __shfl_xor(ss, off);
    float inv = rsqrtf(ss * (1.0f / 128.0f) + 1e-6f);
    float n0 = x0 * inv * wn[lane];
    float n1 = x1 * inv * wn[lane + 64];
    float fr = exp2f(-(float)lane * 0.3114307588956902f);
    float ang = (float)t * fr;
    float c = cosf(ang), s = sinf(ang);
    float y0 = (n0 * c - n1 * s) * scale;
    float y1 = (n1 * c + n0 * s) * scale;
    if (isq) {
        qdst[lane] = f2bf(y0);
        qdst[lane + 64] = f2bf(y1);
    } else {
        kbase[koff_tiled(t, lane)] = f2bf(y0);
        kbase[koff_tiled(t, lane + 64)] = f2bf(y1);
    }
}

// ---------------- V slice: fp32 -> fp16 tiled layout for PV A-operand ----------------
// Tile = 64 keys x 128 dims, 8192 halfs. chunk(dblk,kcp,quad,l15) holds
// V[k = kcp*32 + h*16 + quad*4 + j][d = dblk*16 + l15] at elem h*4+j.
__global__ __launch_bounds__(256) void vtrans_kernel(const float* __restrict__ qkv,
                                                     _Float16* __restrict__ vT) {
    __shared__ _Float16 tile[64 * 128];
    int tid = threadIdx.x;
    int t64 = blockIdx.x & 31, hk = (blockIdx.x >> 5) & 7, b = blockIdx.x >> 8;
    int t0 = t64 * 64;
#pragma unroll
    for (int i = 0; i < 8; i++) {
        int ix = i * 256 + tid;           // 2048 float4 chunks
        int tl = ix >> 5, dc = (ix & 31) * 4;
        float4 v = *(const float4*)(qkv + (size_t)(b * Tn + t0 + tl) * 4096 + 3072 + hk * 128 + dc);
        tile[tl * 128 + dc + 0] = (_Float16)v.x;
        tile[tl * 128 + dc + 1] = (_Float16)v.y;
        tile[tl * 128 + dc + 2] = (_Float16)v.z;
        tile[tl * 128 + dc + 3] = (_Float16)v.w;
    }
    __syncthreads();
    _Float16* out = vT + (((size_t)(b * HKVn + hk) * 32 + t64) * 8192);
#pragma unroll
    for (int i = 0; i < 4; i++) {
        int oc = i * 256 + tid;           // 1024 16B chunks
        int dblk = oc >> 7, kcp = (oc >> 6) & 1, qd = (oc >> 4) & 3, l15 = oc & 15;
        f16x8 st;
#pragma unroll
        for (int e = 0; e < 8; e++) {
            int hh = e >> 2, jj = e & 3;
            int t = kcp * 32 + hh * 16 + qd * 4 + jj;
            int d = dblk * 16 + l15;
            st[e] = tile[t * 128 + d];
        }
        *(f16x8*)(out + oc * 8) = st;
    }
}

// ---------------- flash attention v3: S^T trick + dbuf prefetch + balanced sched ------
__global__ __launch_bounds__(256, 2) void attn_kernel(const unsigned short* __restrict__ q_bf,
                                                      const unsigned short* __restrict__ k_glob,
                                                      const _Float16* __restrict__ v_glob,
                                                      unsigned short* __restrict__ ctx) {
    // double-buffered: buf b at smem + b*32768; K tile 16KB @+0, V tile 16KB @+16384
    __shared__ char smem[65536];
    int tid = threadIdx.x;
    int w = tid >> 6, lane = tid & 63, quad = lane >> 4, l15 = lane & 15;
    int bid = blockIdx.x;
    // balanced scheduling: blocks c and c+256 land on the same CU (round-robin
    // heuristic) and get qblk 15-j and j -> per-CU work is constant (36 tiles)
    int u = bid & 255, halfg = bid >> 8;
    int j = u & 7, h = (u >> 3) & 15, b = (u >> 7) & 1;
    int qblk = halfg ? j : 15 - j;
    int hkv = h >> 1;
    int qb = qblk * 128;
    int qw0 = qb + w * 32;               // this wave's first q row

    const unsigned short* qp = q_bf + (size_t)(b * Hq + h) * Tn * 128;
    const unsigned short* ktile = k_glob + (size_t)(b * HKVn + hkv) * 32 * 8192;
    const _Float16* vtile = v_glob + (size_t)(b * HKVn + hkv) * 32 * 8192;

    // Q fragments (B-operand of S^T mfma): lane l15 = q row, d = f*32+quad*8+j
    bfrag8 qf[2][4];
#pragma unroll
    for (int g = 0; g < 2; g++) {
        int row = qw0 + g * 16 + l15;
#pragma unroll
        for (int f = 0; f < 4; f++)
            qf[g][f] = *(const bfrag8*)(qp + (size_t)row * 128 + f * 32 + quad * 8);
    }

    facc4 o0[8], o1[8];
#pragma unroll
    for (int jj = 0; jj < 8; jj++) { o0[jj] = facc4{0.f,0.f,0.f,0.f}; o1[jj] = facc4{0.f,0.f,0.f,0.f}; }
    float m0 = -__builtin_inff(), m1 = -__builtin_inff(), l0 = 0.f, l1 = 0.f;

    int nkb = qb / 64 + 2;

    // prologue: stage tile 0 into buffer 0
    {
#pragma unroll
        for (int i = 0; i < 4; i++) {
            const unsigned short* gk = ktile + (size_t)(i * 256 + tid) * 8;
            __builtin_amdgcn_global_load_lds((const __attribute__((address_space(1))) void*)gk,
                (__attribute__((address_space(3))) void*)(smem + i * 4096 + w * 1024), 16, 0, 0);
            const _Float16* gv = vtile + (size_t)(i * 256 + tid) * 8;
            __builtin_amdgcn_global_load_lds((const __attribute__((address_space(1))) void*)gv,
                (__attribute__((address_space(3))) void*)(smem + 16384 + i * 4096 + w * 1024), 16, 0, 0);
        }
    }

    for (int ib = 0; ib < nkb; ib++) {
        int kb = ib * 64;
        // drains tile-ib loads (issued one full compute phase ago -> cheap) and
        // guarantees every wave is done READING the buffer we're about to refill
        __syncthreads();
        if (ib + 1 < nkb) {
            char* nb = smem + ((ib + 1) & 1) * 32768;
#pragma unroll
            for (int i = 0; i < 4; i++) {
                const unsigned short* gk = ktile + (size_t)(ib + 1) * 8192 + (i * 256 + tid) * 8;
                __builtin_amdgcn_global_load_lds((const __attribute__((address_space(1))) void*)gk,
                    (__attribute__((address_space(3))) void*)(nb + i * 4096 + w * 1024), 16, 0, 0);
                const _Float16* gv = vtile + (size_t)(ib + 1) * 8192 + (i * 256 + tid) * 8;
                __builtin_amdgcn_global_load_lds((const __attribute__((address_space(1))) void*)gv,
                    (__attribute__((address_space(3))) void*)(nb + 16384 + i * 4096 + w * 1024), 16, 0, 0);
            }
        }
        char* cb = smem + (ib & 1) * 32768;
        if (kb <= qw0 + 31) {
            // S^T = K·Q^T : lane holds S^T[k = kb+kc*16+quad*4+r][q = qbase+l15]
            facc4 s0[4], s1[4];
#pragma unroll
            for (int kc = 0; kc < 4; kc++) {
                bfrag8 kf[4];
#pragma unroll
                for (int f = 0; f < 4; f++)
                    kf[f] = *(const bfrag8*)(cb + (((kc * 4 + f) * 64 + lane) << 4));
                facc4 a = facc4{0.f,0.f,0.f,0.f}, bq = facc4{0.f,0.f,0.f,0.f};
#pragma unroll
                for (int f = 0; f < 4; f++) {
                    a  = __builtin_amdgcn_mfma_f32_16x16x32_bf16(kf[f], qf[0][f], a, 0, 0, 0);
                    bq = __builtin_amdgcn_mfma_f32_16x16x32_bf16(kf[f], qf[1][f], bq, 0, 0, 0);
                }
                s0[kc] = a; s1[kc] = bq;
            }
            if (kb + 63 > qw0) {   // diagonal: apply causal mask
                int q0 = qw0 + l15, q1 = q0 + 16;
#pragma unroll
                for (int kc = 0; kc < 4; kc++)
#pragma unroll
                    for (int r = 0; r < 4; r++) {
                        int k = kb + kc * 16 + quad * 4 + r;
                        if (k > q0) s0[kc][r] = -__builtin_inff();
                        if (k > q1) s1[kc][r] = -__builtin_inff();
                    }
            }
            float mx0 = s0[0][0], mx1 = s1[0][0];
#pragma unroll
            for (int kc = 0; kc < 4; kc++)
#pragma unroll
                for (int r = 0; r < 4; r++) {
                    mx0 = fmaxf(mx0, s0[kc][r]); mx1 = fmaxf(mx1, s1[kc][r]);
                }
            mx0 = fmaxf(mx0, __shfl_xor(mx0, 16)); mx0 = fmaxf(mx0, __shfl_xor(mx0, 32));
            mx1 = fmaxf(mx1, __shfl_xor(mx1, 16)); mx1 = fmaxf(mx1, __shfl_xor(mx1, 32));
            float mn0 = fmaxf(m0, mx0), mn1 = fmaxf(m1, mx1);
            float alpha0 = __expf(m0 - mn0), alpha1 = __expf(m1 - mn1);
            m0 = mn0; m1 = mn1;
            float rs0 = 0.f, rs1 = 0.f;
#pragma unroll
            for (int kc = 0; kc < 4; kc++)
#pragma unroll
                for (int r = 0; r < 4; r++) {
                    s0[kc][r] = __expf(s0[kc][r] - m0); rs0 += s0[kc][r];
                    s1[kc][r] = __expf(s1[kc][r] - m1); rs1 += s1[kc][r];
                }
            rs0 += __shfl_xor(rs0, 16); rs0 += __shfl_xor(rs0, 32);
            rs1 += __shfl_xor(rs1, 16); rs1 += __shfl_xor(rs1, 32);
            l0 = l0 * alpha0 + rs0; l1 = l1 * alpha1 + rs1;
#pragma unroll
            for (int jj = 0; jj < 8; jj++)
#pragma unroll
                for (int r = 0; r < 4; r++) { o0[jj][r] *= alpha0; o1[jj][r] *= alpha1; }
            // P^T C-regs -> fp16 B-operands (k = quad*4+j matches 16x16x16 layout)
            f16x4 pb0[4], pb1[4];
#pragma unroll
            for (int kc = 0; kc < 4; kc++) {
                pb0[kc] = f16x4{(_Float16)s0[kc][0], (_Float16)s0[kc][1],
                                (_Float16)s0[kc][2], (_Float16)s0[kc][3]};
                pb1[kc] = f16x4{(_Float16)s1[kc][0], (_Float16)s1[kc][1],
                                (_Float16)s1[kc][2], (_Float16)s1[kc][3]};
            }
            // PV: O^T[d][q] += V^T[d][k]·P^T[k][q]
#pragma unroll
            for (int kcp = 0; kcp < 2; kcp++)
#pragma unroll
                for (int dblk = 0; dblk < 8; dblk++) {
                    f16x8 vv = *(const f16x8*)(cb + 16384 + (((dblk * 2 + kcp) * 64 + lane) << 4));
                    f16x4 a0 = f16x4{vv[0], vv[1], vv[2], vv[3]};
                    f16x4 a1 = f16x4{vv[4], vv[5], vv[6], vv[7]};
                    o0[dblk] = __builtin_amdgcn_mfma_f32_16x16x16f16(a0, pb0[kcp*2],   o0[dblk], 0, 0, 0);
                    o0[dblk] = __builtin_amdgcn_mfma_f32_16x16x16f16(a1, pb0[kcp*2+1], o0[dblk], 0, 0, 0);
                    o1[dblk] = __builtin_amdgcn_mfma_f32_16x16x16f16(a0, pb1[kcp*2],   o1[dblk], 0, 0, 0);
                    o1[dblk] = __builtin_amdgcn_mfma_f32_16x16x16f16(a1, pb1[kcp*2+1], o1[dblk], 0, 0, 0);
                }
        }
    }
    // epilogue: O^T C-layout: lane holds O[q = base+l15][d = dblk*16+quad*4+r]
    float inv0 = 1.0f / l0, inv1 = 1.0f / l1;
#pragma unroll
    for (int g = 0; g < 2; g++) {
        int q = qw0 + g * 16 + l15;
        float invl = g ? inv1 : inv0;
#pragma unroll
        for (int dblk = 0; dblk < 8; dblk++) {
            facc4 ov = g ? o1[dblk] : o0[dblk];
            ushort4 st;
            st.x = f2bf(ov[0] * invl); st.y = f2bf(ov[1] * invl);
            st.z = f2bf(ov[2] * invl); st.w = f2bf(ov[3] * invl);
            *(ushort4*)(ctx + ((size_t)(b * Tn + q)) * 2048 + h * 128 + dblk * 16 + quad * 4) = st;
        }
    }
}

extern "C" void kernel_launch(void* const* d_in, const int* in_sizes, int n_in,
                              void* d_out, int out_size, void* d_ws, size_t ws_size,
                              hipStream_t stream) {
    (void)in_sizes; (void)n_in; (void)out_size; (void)ws_size;
    const float* x  = (const float*)d_in[0];
    const float* wq = (const float*)d_in[1];
    const float* wk = (const float*)d_in[2];
    const float* wv = (const float*)d_in[3];
    const float* wo = (const float*)d_in[4];
    const float* qw = (const float*)d_in[5];
    const float* kw = (const float*)d_in[6];
    float* out = (float*)d_out;
    char* ws = (char*)d_ws;

    unsigned short* x_bf    = (unsigned short*)(ws);               // 16.78 MB
    unsigned short* wqkv_bf = (unsigned short*)(ws + 16777216);    // 16.78 MB
    unsigned short* wo_bf   = (unsigned short*)(ws + 33554432);    //  8.39 MB
    float*          qkv_f   = (float*)(ws + 41943040);             // 67.11 MB
    unsigned short* q_bf    = (unsigned short*)(ws + 109051904);   // 16.78 MB [B][H][T][128]
    unsigned short* k_bf    = (unsigned short*)(ws + 125829120);   //  8.39 MB tiled
    _Float16*       vT_f16  = (_Float16*)(ws + 134217728);         //  8.39 MB tiled fp16
    unsigned short* ctx_bf  = (unsigned short*)(ws + 142606336);   // 16.78 MB [4096][2048]

    cvt_kernel<<<8192, 256, 0, stream>>>(x, x_bf, 2097152);
    cvt_kernel<<<4096, 256, 0, stream>>>(wq, wqkv_bf, 1048576);
    cvt_kernel<<<2048, 256, 0, stream>>>(wk, wqkv_bf + 4194304, 524288);
    cvt_kernel<<<2048, 256, 0, stream>>>(wv, wqkv_bf + 6291456, 524288);
    cvt_kernel<<<4096, 256, 0, stream>>>(wo, wo_bf, 1048576);
    gemm_bt<<<dim3(32, 32), 256, 0, stream>>>(x_bf, wqkv_bf, qkv_f, 4096, 4096, 2048);
    normrope_kernel<<<24576, 256, 0, stream>>>(qkv_f, qw, kw, q_bf, k_bf);
    vtrans_kernel<<<512, 256, 0, stream>>>(qkv_f, vT_f16);
    attn_kernel<<<512, 256, 0, stream>>>(q_bf, k_bf, vT_f16, ctx_bf);
    gemm_bt<<<dim3(16, 32), 256, 0, stream>>>(ctx_bf, wo_bf, out, 4096, 2048, 2048);
}

// Round 4
// 331.664 us; speedup vs baseline: 1.8434x; 1.1304x over previous
//
#include <hip/hip_runtime.h>
#include <cstdint>

#define Hq 16
#define HKVn 8
#define DHn 128
#define Tn 2048
#define Bn 2
#define Dm 2048
#define BT (Bn*Tn)   // 4096

typedef __attribute__((ext_vector_type(8))) short bfrag8;   // 8 bf16 (4 VGPRs)
typedef __attribute__((ext_vector_type(4))) float facc4;    // 4 fp32 acc
typedef __attribute__((ext_vector_type(4))) _Float16 f16x4; // 4 fp16 (2 VGPRs)
typedef __attribute__((ext_vector_type(8))) _Float16 f16x8; // 8 fp16 (4 VGPRs)
typedef __attribute__((ext_vector_type(8))) unsigned short us8;

__device__ __forceinline__ unsigned short f2bf(float f) {
    union { float f; unsigned int u; } v; v.f = f;
    unsigned int u = v.u;
    unsigned int r = (u + 0x7FFFu + ((u >> 16) & 1u)) >> 16;
    return (unsigned short)r;
}
__device__ __forceinline__ float bf2f(unsigned short u) {
    union { unsigned int u; float f; } v; v.u = ((unsigned int)u) << 16;
    return v.f;
}

// ---------------- fused fp32 -> bf16 convert for all 5 inputs ----------------
__global__ __launch_bounds__(256) void cvt_all(const float* __restrict__ x,
                                               const float* __restrict__ wq,
                                               const float* __restrict__ wk,
                                               const float* __restrict__ wv,
                                               const float* __restrict__ wo,
                                               unsigned short* __restrict__ x_bf,
                                               unsigned short* __restrict__ wqkv_bf,
                                               unsigned short* __restrict__ wo_bf) {
    int i = blockIdx.x * 256 + threadIdx.x;   // float4 index, total 5242880
    const float4* src; ushort4* dst;
    if (i < 2097152)      { src = (const float4*)x  + i;            dst = (ushort4*)x_bf + i; }
    else if (i < 3145728) { src = (const float4*)wq + (i-2097152);  dst = (ushort4*)wqkv_bf + (i-2097152); }
    else if (i < 3670016) { src = (const float4*)wk + (i-3145728);  dst = (ushort4*)wqkv_bf + 1048576 + (i-3145728); }
    else if (i < 4194304) { src = (const float4*)wv + (i-3670016);  dst = (ushort4*)wqkv_bf + 1572864 + (i-3670016); }
    else                  { src = (const float4*)wo + (i-4194304);  dst = (ushort4*)wo_bf + (i-4194304); }
    float4 v = *src;
    ushort4 y;
    y.x = f2bf(v.x); y.y = f2bf(v.y); y.z = f2bf(v.z); y.w = f2bf(v.w);
    *dst = y;
}

// K tiled-layout element offset within a (b,hkv) plane (attn-kernel K layout).
__device__ __forceinline__ size_t koff_tiled(int t, int d) {
    int kc = (t >> 4) & 3, l15 = t & 15;
    int f = d >> 5, qd = (d >> 3) & 3, j = d & 7;
    return (size_t)(t >> 6) * 8192 + ((((kc * 4 + f) * 64 + qd * 16 + l15) << 3) + j);
}

// ---------------- bf16 GEMM (out-proj): C[M][N] = A[M][K] @ B[N][K]^T, fp32 out ------
// BK=64, XOR-swizzled LDS chunks (conflict-free frag reads), 128x128 tile.
__global__ __launch_bounds__(256) void gemm_bt(const unsigned short* __restrict__ A,
                                               const unsigned short* __restrict__ Bm,
                                               float* __restrict__ C,
                                               int M, int N, int K) {
    __shared__ char smem[32768];   // As[128][64] @0, Bs[128][64] @16384
    int tid = threadIdx.x;
    int w = tid >> 6, lane = tid & 63, quad = lane >> 4, l15 = lane & 15;
    int wr = w >> 1, wc = w & 1;
    int rowBase = blockIdx.y * 128, colBase = blockIdx.x * 128;
    facc4 acc[4][4];
#pragma unroll
    for (int i = 0; i < 4; i++)
#pragma unroll
        for (int j = 0; j < 4; j++) acc[i][j] = facc4{0.f, 0.f, 0.f, 0.f};

    for (int k0 = 0; k0 < K; k0 += 64) {
        __syncthreads();
#pragma unroll
        for (int i4 = 0; i4 < 4; i4++) {
            int c = i4 * 256 + tid;
            int r = c >> 3, kkg = (c & 7) ^ (r & 7);
            const unsigned short* ga = A + (size_t)(rowBase + r) * K + k0 + kkg * 8;
            __builtin_amdgcn_global_load_lds((const __attribute__((address_space(1))) void*)ga,
                (__attribute__((address_space(3))) void*)(smem + i4 * 4096 + w * 1024), 16, 0, 0);
            const unsigned short* gb = Bm + (size_t)(colBase + r) * K + k0 + kkg * 8;
            __builtin_amdgcn_global_load_lds((const __attribute__((address_space(1))) void*)gb,
                (__attribute__((address_space(3))) void*)(smem + 16384 + i4 * 4096 + w * 1024), 16, 0, 0);
        }
        __syncthreads();
#pragma unroll
        for (int kh = 0; kh < 2; kh++) {
            bfrag8 af[4], bf[4];
#pragma unroll
            for (int i = 0; i < 4; i++) {
                int row = wr * 64 + i * 16 + l15;
                int ch = row * 8 + ((kh * 4 + quad) ^ (row & 7));
                af[i] = *(const bfrag8*)(smem + ch * 16);
            }
#pragma unroll
            for (int j = 0; j < 4; j++) {
                int row = wc * 64 + j * 16 + l15;
                int ch = row * 8 + ((kh * 4 + quad) ^ (row & 7));
                bf[j] = *(const bfrag8*)(smem + 16384 + ch * 16);
            }
#pragma unroll
            for (int i = 0; i < 4; i++)
#pragma unroll
                for (int j = 0; j < 4; j++)
                    acc[i][j] = __builtin_amdgcn_mfma_f32_16x16x32_bf16(af[i], bf[j], acc[i][j], 0, 0, 0);
        }
    }
#pragma unroll
    for (int i = 0; i < 4; i++)
#pragma unroll
        for (int j = 0; j < 4; j++)
#pragma unroll
            for (int r = 0; r < 4; r++) {
                int row = rowBase + wr * 64 + i * 16 + quad * 4 + r;
                int col = colBase + wc * 64 + j * 16 + l15;
                C[(size_t)row * N + col] = acc[i][j][r];
            }
}

// ---------------- fused QKV GEMM + RMSNorm + RoPE + relayout --------------------------
// grid (32, 32): blockIdx.x<16 -> q head, 16..23 -> k head, 24..31 -> v head.
__global__ __launch_bounds__(256) void gemm_qkv_fused(const unsigned short* __restrict__ A,
                                                      const unsigned short* __restrict__ Bm,
                                                      const float* __restrict__ qw,
                                                      const float* __restrict__ kw,
                                                      unsigned short* __restrict__ q_bf,
                                                      unsigned short* __restrict__ k_bf,
                                                      _Float16* __restrict__ vT) {
    // main loop: As[128][64] @0 (16KB), Bs @16384 (16KB)
    // epilogue: bf16 tile [128][136] @0 (34816B), row sums @34816 (1KB)
    __shared__ char smem[35840];
    const int K = 2048, Nn = 4096;
    int tid = threadIdx.x;
    int w = tid >> 6, lane = tid & 63, quad = lane >> 4, l15 = lane & 15;
    int wr = w >> 1, wc = w & 1;
    int bx = blockIdx.x;
    int rowBase = blockIdx.y * 128, colBase = bx * 128;
    (void)Nn;
    facc4 acc[4][4];
#pragma unroll
    for (int i = 0; i < 4; i++)
#pragma unroll
        for (int j = 0; j < 4; j++) acc[i][j] = facc4{0.f, 0.f, 0.f, 0.f};

    for (int k0 = 0; k0 < K; k0 += 64) {
        __syncthreads();
#pragma unroll
        for (int i4 = 0; i4 < 4; i4++) {
            int c = i4 * 256 + tid;
            int r = c >> 3, kkg = (c & 7) ^ (r & 7);
            const unsigned short* ga = A + (size_t)(rowBase + r) * K + k0 + kkg * 8;
            __builtin_amdgcn_global_load_lds((const __attribute__((address_space(1))) void*)ga,
                (__attribute__((address_space(3))) void*)(smem + i4 * 4096 + w * 1024), 16, 0, 0);
            const unsigned short* gb = Bm + (size_t)(colBase + r) * K + k0 + kkg * 8;
            __builtin_amdgcn_global_load_lds((const __attribute__((address_space(1))) void*)gb,
                (__attribute__((address_space(3))) void*)(smem + 16384 + i4 * 4096 + w * 1024), 16, 0, 0);
        }
        __syncthreads();
#pragma unroll
        for (int kh = 0; kh < 2; kh++) {
            bfrag8 af[4], bf[4];
#pragma unroll
            for (int i = 0; i < 4; i++) {
                int row = wr * 64 + i * 16 + l15;
                int ch = row * 8 + ((kh * 4 + quad) ^ (row & 7));
                af[i] = *(const bfrag8*)(smem + ch * 16);
            }
#pragma unroll
            for (int j = 0; j < 4; j++) {
                int row = wc * 64 + j * 16 + l15;
                int ch = row * 8 + ((kh * 4 + quad) ^ (row & 7));
                bf[j] = *(const bfrag8*)(smem + 16384 + ch * 16);
            }
#pragma unroll
            for (int i = 0; i < 4; i++)
#pragma unroll
                for (int j = 0; j < 4; j++)
                    acc[i][j] = __builtin_amdgcn_mfma_f32_16x16x32_bf16(af[i], bf[j], acc[i][j], 0, 0, 0);
        }
    }

    if (bx >= 24) {
        // ---- V epilogue: fp32 acc -> fp16 tiled layout, direct from regs ----
        int hv = bx - 24;
        int gt0 = rowBase + wr * 64;
        int bb = gt0 >> 11;
        int t64 = (gt0 & 2047) >> 6;
        _Float16* base = vT + ((size_t)(bb * 8 + hv) * 32 + t64) * 8192;
#pragma unroll
        for (int i = 0; i < 4; i++) {
            int kcp = i >> 1, hh = i & 1;
#pragma unroll
            for (int j = 0; j < 4; j++) {
                int dblk = wc * 4 + j;
                f16x4 pv;
#pragma unroll
                for (int r = 0; r < 4; r++) pv[r] = (_Float16)acc[i][j][r];
                *(f16x4*)(base + (((dblk * 2 + kcp) * 64 + quad * 16 + l15) * 8) + hh * 4) = pv;
            }
        }
        return;
    }

    // ---- Q/K epilogue: RMSNorm + RoPE + relayout ----
    const float* wn = (bx < 16) ? qw : kw;
    // q also gets 1/sqrt(128)*log2(e) folded in (attn uses exp2)
    const float osc = (bx < 16) ? (0.08838834764831845f * 1.4426950408889634f) : 1.0f;
    float* sums = (float*)(smem + 34816);
    float ssum[4][4];
#pragma unroll
    for (int i = 0; i < 4; i++)
#pragma unroll
        for (int r = 0; r < 4; r++) {
            float s = 0.f;
#pragma unroll
            for (int j = 0; j < 4; j++) s += acc[i][j][r] * acc[i][j][r];
            s += __shfl_xor(s, 1); s += __shfl_xor(s, 2);
            s += __shfl_xor(s, 4); s += __shfl_xor(s, 8);
            ssum[i][r] = s;
        }
    if (l15 == 0) {
#pragma unroll
        for (int i = 0; i < 4; i++)
#pragma unroll
            for (int r = 0; r < 4; r++)
                sums[wc * 128 + wr * 64 + i * 16 + quad * 4 + r] = ssum[i][r];
    }
    __syncthreads();   // sums visible; all waves done reading As/Bs
    unsigned short* tile = (unsigned short*)smem;   // [128][136] bf16
    float wcol[4];
#pragma unroll
    for (int j = 0; j < 4; j++) wcol[j] = wn[wc * 64 + j * 16 + l15];
#pragma unroll
    for (int i = 0; i < 4; i++)
#pragma unroll
        for (int r = 0; r < 4; r++) {
            int row = wr * 64 + i * 16 + quad * 4 + r;
            float tot = sums[row] + sums[128 + row];
            float inv = rsqrtf(tot * (1.0f / 128.0f) + 1e-6f);
#pragma unroll
            for (int j = 0; j < 4; j++)
                tile[row * 136 + wc * 64 + j * 16 + l15] = f2bf(acc[i][j][r] * inv * wcol[j]);
        }
    __syncthreads();
    // RoPE pairing: 2 threads per row, 32 dims each (chunks of 8)
    {
        int row = tid >> 1, d0 = (tid & 1) * 32;
        int gt = rowBase + row;
        int t = gt & 2047, bb = gt >> 11;
        unsigned short* qrow = q_bf + ((size_t)(bb * 16 + bx) * 2048 + t) * 128;
        unsigned short* kplane = k_bf + (size_t)(bb * 8 + (bx - 16)) * 2048 * 128;
        float tf = (float)t;
#pragma unroll
        for (int dc = 0; dc < 32; dc += 8) {
            int db = d0 + dc;
            us8 n0u = *(const us8*)(tile + row * 136 + db);
            us8 n1u = *(const us8*)(tile + row * 136 + db + 64);
            us8 p0, p1;
#pragma unroll
            for (int e = 0; e < 8; e++) {
                float fr = exp2f(-(float)(db + e) * 0.3114307588956902f);
                float sv, cv;
                __sincosf(tf * fr, &sv, &cv);
                float a0 = bf2f(n0u[e]), a1 = bf2f(n1u[e]);
                p0[e] = f2bf((a0 * cv - a1 * sv) * osc);
                p1[e] = f2bf((a1 * cv + a0 * sv) * osc);
            }
            if (bx < 16) {
                *(us8*)(qrow + db) = p0;
                *(us8*)(qrow + db + 64) = p1;
            } else {
                *(us8*)(kplane + koff_tiled(t, db)) = p0;
                *(us8*)(kplane + koff_tiled(t, db + 64)) = p1;
            }
        }
    }
}

// ---------------- flash attention: S^T trick + dbuf prefetch + balanced sched ---------
__global__ __launch_bounds__(256, 2) void attn_kernel(const unsigned short* __restrict__ q_bf,
                                                      const unsigned short* __restrict__ k_glob,
                                                      const _Float16* __restrict__ v_glob,
                                                      unsigned short* __restrict__ ctx) {
    __shared__ char smem[65536];   // dbuf: K 16KB + V 16KB per buffer
    int tid = threadIdx.x;
    int w = tid >> 6, lane = tid & 63, quad = lane >> 4, l15 = lane & 15;
    int bid = blockIdx.x;
    int u = bid & 255, halfg = bid >> 8;
    int j = u & 7, h = (u >> 3) & 15, b = (u >> 7) & 1;
    int qblk = halfg ? j : 15 - j;
    int hkv = h >> 1;
    int qb = qblk * 128;
    int qw0 = qb + w * 32;

    const unsigned short* qp = q_bf + (size_t)(b * Hq + h) * Tn * 128;
    const unsigned short* ktile = k_glob + (size_t)(b * HKVn + hkv) * 32 * 8192;
    const _Float16* vtile = v_glob + (size_t)(b * HKVn + hkv) * 32 * 8192;

    bfrag8 qf[2][4];
#pragma unroll
    for (int g = 0; g < 2; g++) {
        int row = qw0 + g * 16 + l15;
#pragma unroll
        for (int f = 0; f < 4; f++)
            qf[g][f] = *(const bfrag8*)(qp + (size_t)row * 128 + f * 32 + quad * 8);
    }

    facc4 o0[8], o1[8];
#pragma unroll
    for (int jj = 0; jj < 8; jj++) { o0[jj] = facc4{0.f,0.f,0.f,0.f}; o1[jj] = facc4{0.f,0.f,0.f,0.f}; }
    float m0 = -__builtin_inff(), m1 = -__builtin_inff(), l0 = 0.f, l1 = 0.f;

    int nkb = qb / 64 + 2;
#pragma unroll
    for (int i = 0; i < 4; i++) {
        const unsigned short* gk = ktile + (size_t)(i * 256 + tid) * 8;
        __builtin_amdgcn_global_load_lds((const __attribute__((address_space(1))) void*)gk,
            (__attribute__((address_space(3))) void*)(smem + i * 4096 + w * 1024), 16, 0, 0);
        const _Float16* gv = vtile + (size_t)(i * 256 + tid) * 8;
        __builtin_amdgcn_global_load_lds((const __attribute__((address_space(1))) void*)gv,
            (__attribute__((address_space(3))) void*)(smem + 16384 + i * 4096 + w * 1024), 16, 0, 0);
    }

    for (int ib = 0; ib < nkb; ib++) {
        int kb = ib * 64;
        __syncthreads();
        if (ib + 1 < nkb) {
            char* nb = smem + ((ib + 1) & 1) * 32768;
#pragma unroll
            for (int i = 0; i < 4; i++) {
                const unsigned short* gk = ktile + (size_t)(ib + 1) * 8192 + (i * 256 + tid) * 8;
                __builtin_amdgcn_global_load_lds((const __attribute__((address_space(1))) void*)gk,
                    (__attribute__((address_space(3))) void*)(nb + i * 4096 + w * 1024), 16, 0, 0);
                const _Float16* gv = vtile + (size_t)(ib + 1) * 8192 + (i * 256 + tid) * 8;
                __builtin_amdgcn_global_load_lds((const __attribute__((address_space(1))) void*)gv,
                    (__attribute__((address_space(3))) void*)(nb + 16384 + i * 4096 + w * 1024), 16, 0, 0);
            }
        }
        char* cb = smem + (ib & 1) * 32768;
        if (kb <= qw0 + 31) {
            facc4 s0[4], s1[4];
#pragma unroll
            for (int kc = 0; kc < 4; kc++) {
                bfrag8 kf[4];
#pragma unroll
                for (int f = 0; f < 4; f++)
                    kf[f] = *(const bfrag8*)(cb + (((kc * 4 + f) * 64 + lane) << 4));
                facc4 a = facc4{0.f,0.f,0.f,0.f}, bq = facc4{0.f,0.f,0.f,0.f};
#pragma unroll
                for (int f = 0; f < 4; f++) {
                    a  = __builtin_amdgcn_mfma_f32_16x16x32_bf16(kf[f], qf[0][f], a, 0, 0, 0);
                    bq = __builtin_amdgcn_mfma_f32_16x16x32_bf16(kf[f], qf[1][f], bq, 0, 0, 0);
                }
                s0[kc] = a; s1[kc] = bq;
            }
            if (kb + 63 > qw0) {
                int q0 = qw0 + l15, q1 = q0 + 16;
#pragma unroll
                for (int kc = 0; kc < 4; kc++)
#pragma unroll
                    for (int r = 0; r < 4; r++) {
                        int k = kb + kc * 16 + quad * 4 + r;
                        if (k > q0) s0[kc][r] = -__builtin_inff();
                        if (k > q1) s1[kc][r] = -__builtin_inff();
                    }
            }
            float mx0 = s0[0][0], mx1 = s1[0][0];
#pragma unroll
            for (int kc = 0; kc < 4; kc++)
#pragma unroll
                for (int r = 0; r < 4; r++) {
                    mx0 = fmaxf(mx0, s0[kc][r]); mx1 = fmaxf(mx1, s1[kc][r]);
                }
            mx0 = fmaxf(mx0, __shfl_xor(mx0, 16)); mx0 = fmaxf(mx0, __shfl_xor(mx0, 32));
            mx1 = fmaxf(mx1, __shfl_xor(mx1, 16)); mx1 = fmaxf(mx1, __shfl_xor(mx1, 32));
            float mn0 = fmaxf(m0, mx0), mn1 = fmaxf(m1, mx1);
            float alpha0 = exp2f(m0 - mn0), alpha1 = exp2f(m1 - mn1);
            m0 = mn0; m1 = mn1;
            float rs0 = 0.f, rs1 = 0.f;
#pragma unroll
            for (int kc = 0; kc < 4; kc++)
#pragma unroll
                for (int r = 0; r < 4; r++) {
                    s0[kc][r] = exp2f(s0[kc][r] - m0); rs0 += s0[kc][r];
                    s1[kc][r] = exp2f(s1[kc][r] - m1); rs1 += s1[kc][r];
                }
            rs0 += __shfl_xor(rs0, 16); rs0 += __shfl_xor(rs0, 32);
            rs1 += __shfl_xor(rs1, 16); rs1 += __shfl_xor(rs1, 32);
            l0 = l0 * alpha0 + rs0; l1 = l1 * alpha1 + rs1;
#pragma unroll
            for (int jj = 0; jj < 8; jj++)
#pragma unroll
                for (int r = 0; r < 4; r++) { o0[jj][r] *= alpha0; o1[jj][r] *= alpha1; }
            f16x4 pb0[4], pb1[4];
#pragma unroll
            for (int kc = 0; kc < 4; kc++) {
                pb0[kc] = f16x4{(_Float16)s0[kc][0], (_Float16)s0[kc][1],
                                (_Float16)s0[kc][2], (_Float16)s0[kc][3]};
                pb1[kc] = f16x4{(_Float16)s1[kc][0], (_Float16)s1[kc][1],
                                (_Float16)s1[kc][2], (_Float16)s1[kc][3]};
            }
#pragma unroll
            for (int kcp = 0; kcp < 2; kcp++)
#pragma unroll
                for (int dblk = 0; dblk < 8; dblk++) {
                    f16x8 vv = *(const f16x8*)(cb + 16384 + (((dblk * 2 + kcp) * 64 + lane) << 4));
                    f16x4 a0 = f16x4{vv[0], vv[1], vv[2], vv[3]};
                    f16x4 a1 = f16x4{vv[4], vv[5], vv[6], vv[7]};
                    o0[dblk] = __builtin_amdgcn_mfma_f32_16x16x16f16(a0, pb0[kcp*2],   o0[dblk], 0, 0, 0);
                    o0[dblk] = __builtin_amdgcn_mfma_f32_16x16x16f16(a1, pb0[kcp*2+1], o0[dblk], 0, 0, 0);
                    o1[dblk] = __builtin_amdgcn_mfma_f32_16x16x16f16(a0, pb1[kcp*2],   o1[dblk], 0, 0, 0);
                    o1[dblk] = __builtin_amdgcn_mfma_f32_16x16x16f16(a1, pb1[kcp*2+1], o1[dblk], 0, 0, 0);
                }
        }
    }
    float inv0 = 1.0f / l0, inv1 = 1.0f / l1;
#pragma unroll
    for (int g = 0; g < 2; g++) {
        int q = qw0 + g * 16 + l15;
        float invl = g ? inv1 : inv0;
#pragma unroll
        for (int dblk = 0; dblk < 8; dblk++) {
            facc4 ov = g ? o1[dblk] : o0[dblk];
            ushort4 st;
            st.x = f2bf(ov[0] * invl); st.y = f2bf(ov[1] * invl);
            st.z = f2bf(ov[2] * invl); st.w = f2bf(ov[3] * invl);
            *(ushort4*)(ctx + ((size_t)(b * Tn + q)) * 2048 + h * 128 + dblk * 16 + quad * 4) = st;
        }
    }
}

extern "C" void kernel_launch(void* const* d_in, const int* in_sizes, int n_in,
                              void* d_out, int out_size, void* d_ws, size_t ws_size,
                              hipStream_t stream) {
    (void)in_sizes; (void)n_in; (void)out_size; (void)ws_size;
    const float* x  = (const float*)d_in[0];
    const float* wq = (const float*)d_in[1];
    const float* wk = (const float*)d_in[2];
    const float* wv = (const float*)d_in[3];
    const float* wo = (const float*)d_in[4];
    const float* qw = (const float*)d_in[5];
    const float* kw = (const float*)d_in[6];
    float* out = (float*)d_out;
    char* ws = (char*)d_ws;

    unsigned short* x_bf    = (unsigned short*)(ws);               // 16.78 MB
    unsigned short* wqkv_bf = (unsigned short*)(ws + 16777216);    // 16.78 MB
    unsigned short* wo_bf   = (unsigned short*)(ws + 33554432);    //  8.39 MB
    unsigned short* q_bf    = (unsigned short*)(ws + 41943040);    // 16.78 MB [B][H][T][128]
    unsigned short* k_bf    = (unsigned short*)(ws + 58720256);    //  8.39 MB tiled
    _Float16*       vT_f16  = (_Float16*)(ws + 67108864);          //  8.39 MB tiled fp16
    unsigned short* ctx_bf  = (unsigned short*)(ws + 75497472);    // 16.78 MB [4096][2048]

    cvt_all<<<20480, 256, 0, stream>>>(x, wq, wk, wv, wo, x_bf, wqkv_bf, wo_bf);
    gemm_qkv_fused<<<dim3(32, 32), 256, 0, stream>>>(x_bf, wqkv_bf, qw, kw, q_bf, k_bf, vT_f16);
    attn_kernel<<<512, 256, 0, stream>>>(q_bf, k_bf, vT_f16, ctx_bf);
    gemm_bt<<<dim3(16, 32), 256, 0, stream>>>(ctx_bf, wo_bf, out, 4096, 2048, 2048);
}